// Round 2
// baseline (154.017 us; speedup 1.0000x reference)
//
#include <hip/hip_runtime.h>
#include <hip/hip_bf16.h>

typedef short bf16x8 __attribute__((ext_vector_type(8)));
typedef float f32x4  __attribute__((ext_vector_type(4)));
typedef int   i32x4  __attribute__((ext_vector_type(4)));

#define NI 256
#define NJ 256
#define NC 128
#define NH 4
#define ND 32

// ---- workspace layout (bytes) ----
// q:   [i][h][256][32] bf16   = 16,384 B per (i,h)
// k:   [i][h][256][40] bf16   = 20,480 B per (i,h)   (padded rows, pad garbage)
// vT:  [i][h][32][264] bf16   = 16,896 B -> padded blob 17,408 B per (i,h)
// tbm: [i][h][256] f32  (tb + mask bias combined)
// O:   [i*256+j][136] bf16 (attention output, padded rows)
#define QG_OFF  0
#define QG_PER  16384
#define KG_OFF  16777216
#define KG_PER  20480
#define VTG_OFF 37748736
#define VTG_PER 17408
#define TBM_OFF 55574528
#define OG_OFF  56623104
#define WS_NEED 74448896

__device__ __forceinline__ short f2bf(float f) {
    return __builtin_bit_cast(short, __float2bfloat16(f));
}
__device__ __forceinline__ float bf2f(short s) {
    unsigned u = ((unsigned)(unsigned short)s) << 16;
    return __builtin_bit_cast(float, u);
}

typedef __attribute__((address_space(1))) const void gvoid_t;
typedef __attribute__((address_space(3))) void svoid_t;
__device__ __forceinline__ void load_lds16(const void* g, void* l) {
    __builtin_amdgcn_global_load_lds((gvoid_t*)g, (svoid_t*)l, 16, 0, 0);
}

// ================= Kernel 1: LN + QKV projection + tb =================
__global__ __launch_bounds__(512, 4)
void k_qkv(const float* __restrict__ x, const float* __restrict__ mask,
           const float* __restrict__ ln_g, const float* __restrict__ ln_b,
           const float* __restrict__ wq, const float* __restrict__ wk,
           const float* __restrict__ wv, const float* __restrict__ wb,
           char* __restrict__ ws)
{
    __shared__ short xn[128][136];   // 34,816 B
    __shared__ short qs[128][32];    //  8,192 B
    __shared__ short ks[128][40];    // 10,240 B
    __shared__ short vts[32][132];   //  8,448 B   (total 61,696 B)

    const int tid  = threadIdx.x;
    const int lane = tid & 63;
    const int wid  = tid >> 6;
    const int g    = lane >> 4;
    const int l16  = lane & 15;
    const int b    = blockIdx.x;
    const int i    = b >> 1;
    const int half = b & 1;
    const int j0   = half * 128;

    short* qg  = (short*)(ws + QG_OFF);
    short* kg  = (short*)(ws + KG_OFF);
    short* vtg = (short*)(ws + VTG_OFF);
    float* tbm = (float*)(ws + TBM_OFF);

    // ---- LayerNorm: 4 threads per token, 32 ch each ----
    {
        const int t  = tid >> 2;
        const int p  = tid & 3;
        const int ch = p * 32;
        const float* xr = x + ((size_t)(i * NJ) + j0 + t) * NC + ch;
        f32x4 vx[8];
        float s0 = 0.f;
        #pragma unroll
        for (int u = 0; u < 8; ++u) {
            vx[u] = *(const f32x4*)(xr + 4 * u);
            s0 += vx[u][0] + vx[u][1] + vx[u][2] + vx[u][3];
        }
        s0 += __shfl_xor(s0, 1);
        s0 += __shfl_xor(s0, 2);
        const float mu = s0 * (1.0f / 128.0f);
        float v0 = 0.f;
        #pragma unroll
        for (int u = 0; u < 8; ++u) {
            #pragma unroll
            for (int e = 0; e < 4; ++e) { float d = vx[u][e] - mu; v0 += d * d; }
        }
        v0 += __shfl_xor(v0, 1);
        v0 += __shfl_xor(v0, 2);
        const float rs = rsqrtf(v0 * (1.0f / 128.0f) + 1e-5f);
        short* xnrow = &xn[t][ch];
        #pragma unroll
        for (int u = 0; u < 4; ++u) {
            f32x4 ga = *(const f32x4*)(ln_g + ch + 8 * u);
            f32x4 gb = *(const f32x4*)(ln_g + ch + 8 * u + 4);
            f32x4 ba = *(const f32x4*)(ln_b + ch + 8 * u);
            f32x4 bb = *(const f32x4*)(ln_b + ch + 8 * u + 4);
            bf16x8 o8;
            #pragma unroll
            for (int e = 0; e < 4; ++e) {
                o8[e]     = f2bf((vx[2*u][e]   - mu) * rs * ga[e] + ba[e]);
                o8[4 + e] = f2bf((vx[2*u+1][e] - mu) * rs * gb[e] + bb[e]);
            }
            *(bf16x8*)(xnrow + 8 * u) = o8;
        }
    }
    __syncthreads();

    // ---- tbm[h][t] = xn[t].wb[h] + 1e9*(mask-1)  (per-query, cancels in softmax) ----
    {
        const int h = tid >> 7;
        const int t = tid & 127;
        const short* xnrow = &xn[t][0];
        const float* wr = wb + h * NC;
        float acc = 0.f;
        #pragma unroll
        for (int c = 0; c < NC; c += 8) {
            bf16x8 xv = *(const bf16x8*)(xnrow + c);
            f32x4 wa = *(const f32x4*)(wr + c);
            f32x4 wz = *(const f32x4*)(wr + c + 4);
            acc += bf2f(xv[0]) * wa[0] + bf2f(xv[1]) * wa[1] + bf2f(xv[2]) * wa[2] + bf2f(xv[3]) * wa[3]
                 + bf2f(xv[4]) * wz[0] + bf2f(xv[5]) * wz[1] + bf2f(xv[6]) * wz[2] + bf2f(xv[7]) * wz[3];
        }
        acc += 1.0e9f * (mask[(size_t)i * NJ + j0 + t] - 1.0f);
        tbm[((size_t)(i * NH) + h) * NJ + j0 + t] = acc;
    }

    const f32x4 z4 = {0.f, 0.f, 0.f, 0.f};

    for (int h = 0; h < NH; ++h) {
        // ---- projection: wave wid owns token tile mt=wid; 6 output sub-tiles ----
        #pragma unroll
        for (int nt = 0; nt < 6; ++nt) {
            const int p_  = nt >> 1;      // 0=q 1=k 2=v
            const int sub = nt & 1;
            const float* W = (p_ == 0) ? wq : ((p_ == 1) ? wk : wv);
            const float* wrow = W + (size_t)(h * ND + sub * 16 + l16) * NC + g * 8;
            bf16x8 bfr[4];
            #pragma unroll
            for (int ks_ = 0; ks_ < 4; ++ks_) {
                f32x4 a = *(const f32x4*)(wrow + ks_ * 32);
                f32x4 c = *(const f32x4*)(wrow + ks_ * 32 + 4);
                bf16x8 t8;
                #pragma unroll
                for (int e = 0; e < 4; ++e) { t8[e] = f2bf(a[e]); t8[4 + e] = f2bf(c[e]); }
                bfr[ks_] = t8;
            }
            const short* xnr = &xn[wid * 16 + l16][g * 8];
            f32x4 acc = z4;
            #pragma unroll
            for (int ks_ = 0; ks_ < 4; ++ks_) {
                bf16x8 av = *(const bf16x8*)(xnr + ks_ * 32);
                acc = __builtin_amdgcn_mfma_f32_16x16x32_bf16(av, bfr[ks_], acc, 0, 0, 0);
            }
            const int tok = wid * 16 + g * 4;
            const int dd  = sub * 16 + l16;
            if (p_ == 0) {
                #pragma unroll
                for (int r = 0; r < 4; ++r) qs[tok + r][dd] = f2bf(acc[r]);
            } else if (p_ == 1) {
                #pragma unroll
                for (int r = 0; r < 4; ++r) ks[tok + r][dd] = f2bf(acc[r]);
            } else {
                #pragma unroll
                for (int r = 0; r < 4; ++r) vts[dd][tok + r] = f2bf(acc[r]);
            }
        }
        __syncthreads();

        // ---- copy staging -> global (coalesced 16B/lane) ----
        const size_t ih = (size_t)(i * NH) + h;
        for (int job = wid; job < 26; job += 8) {
            const char* src;
            char* dst;
            if (job < 8) {
                src = (const char*)qs + job * 1024 + lane * 16;
                dst = (char*)qg + ih * QG_PER + half * 8192 + job * 1024 + lane * 16;
            } else if (job < 18) {
                const int jj = job - 8;
                src = (const char*)ks + jj * 1024 + lane * 16;
                dst = (char*)kg + ih * KG_PER + half * 10240 + jj * 1024 + lane * 16;
            } else {
                const int jj  = job - 18;
                const int row = jj * 4 + (lane >> 4);
                const int cb  = (lane & 15) * 16;
                src = (const char*)vts + row * 264 + cb;
                dst = (char*)vtg + ih * VTG_PER + row * 528 + half * 256 + cb;
            }
            *(i32x4*)dst = *(const i32x4*)src;
        }
        __syncthreads();
    }
}

// ================= Kernel 2: per-(i,h) attention =================
__global__ __launch_bounds__(512, 4)
void k_attn(const char* __restrict__ ws_qkv, short* __restrict__ og)
{
    __shared__ short kls[256][40];   // 20,480 B
    __shared__ char  vls[17408];     // vT rows at 528 B stride
    __shared__ short pbuf[8][16][40];// 10,240 B  (total 48,128 B)

    const int tid  = threadIdx.x;
    const int lane = tid & 63;
    const int wid  = tid >> 6;
    const int g    = lane >> 4;
    const int l16  = lane & 15;
    const int b    = blockIdx.x;
    const int i    = b >> 2;
    const int h    = b & 3;
    const size_t ih = (size_t)(i * NH) + h;

    const short* qg  = (const short*)(ws_qkv + QG_OFF) + ih * (QG_PER / 2);
    const char*  kgp = ws_qkv + KG_OFF + ih * KG_PER;
    const char*  vtp = ws_qkv + VTG_OFF + ih * VTG_PER;
    const float* tbm = (const float*)(ws_qkv + TBM_OFF) + ih * NJ;

    // ---- stage k (20 KB) + vT (17 KB) via async global->LDS ----
    for (int c = wid; c < 37; c += 8) {
        if (c < 20) load_lds16(kgp + c * 1024 + lane * 16, (char*)kls + c * 1024);
        else        load_lds16(vtp + (c - 20) * 1024 + lane * 16, vls + (c - 20) * 1024);
    }
    __syncthreads();

    const float SCALE = 0.17677669529663687f;  // 1/sqrt(32)
    const f32x4 z4 = {0.f, 0.f, 0.f, 0.f};
    char* pb = (char*)&pbuf[wid][0][0];

    #pragma unroll
    for (int qt = 0; qt < 2; ++qt) {
        const int tq = wid * 32 + qt * 16;
        f32x4 tbmb = *(const f32x4*)(tbm + tq + g * 4);

        bf16x8 qf = *(const bf16x8*)(qg + (size_t)(tq + l16) * 32 + g * 8);
        f32x4 s[16];
        #pragma unroll
        for (int kt = 0; kt < 16; ++kt) {
            bf16x8 kf = *(const bf16x8*)(&kls[kt * 16 + l16][g * 8]);
            s[kt] = __builtin_amdgcn_mfma_f32_16x16x32_bf16(qf, kf, z4, 0, 0, 0);
        }
        #pragma unroll
        for (int kt = 0; kt < 16; ++kt)
            #pragma unroll
            for (int r = 0; r < 4; ++r)
                s[kt][r] = fmaf(s[kt][r], SCALE, tbmb[r]);  // fp32: masked rows collapse exactly

        f32x4 mx = s[0];
        #pragma unroll
        for (int kt = 1; kt < 16; ++kt)
            #pragma unroll
            for (int r = 0; r < 4; ++r) mx[r] = fmaxf(mx[r], s[kt][r]);
        #pragma unroll
        for (int d = 1; d < 16; d <<= 1)
            #pragma unroll
            for (int r = 0; r < 4; ++r) mx[r] = fmaxf(mx[r], __shfl_xor(mx[r], d));

        f32x4 sum = z4;
        #pragma unroll
        for (int kt = 0; kt < 16; ++kt)
            #pragma unroll
            for (int r = 0; r < 4; ++r) { s[kt][r] = __expf(s[kt][r] - mx[r]); sum[r] += s[kt][r]; }
        #pragma unroll
        for (int d = 1; d < 16; d <<= 1)
            #pragma unroll
            for (int r = 0; r < 4; ++r) sum[r] += __shfl_xor(sum[r], d);
        f32x4 inv;
        #pragma unroll
        for (int r = 0; r < 4; ++r) inv[r] = 1.0f / sum[r];
        #pragma unroll
        for (int kt = 0; kt < 16; ++kt)
            #pragma unroll
            for (int r = 0; r < 4; ++r) s[kt][r] *= inv[r];

        // ---- PV: per-wave LDS round-trip, 32-key chunks ----
        f32x4 oacc0 = z4, oacc1 = z4;
        #pragma unroll
        for (int c = 0; c < 8; ++c) {
            #pragma unroll
            for (int kk = 0; kk < 2; ++kk) {
                const int kt = c * 2 + kk;
                #pragma unroll
                for (int r = 0; r < 4; ++r)
                    *((short*)(pb + (size_t)(g * 4 + r) * 80) + kk * 16 + l16) = f2bf(s[kt][r]);
            }
            bf16x8 a   = *(const bf16x8*)((const short*)(pb + (size_t)l16 * 80) + g * 8);
            bf16x8 vb0 = *(const bf16x8*)((const short*)(vls + (size_t)l16 * 528) + c * 32 + g * 8);
            bf16x8 vb1 = *(const bf16x8*)((const short*)(vls + (size_t)(16 + l16) * 528) + c * 32 + g * 8);
            oacc0 = __builtin_amdgcn_mfma_f32_16x16x32_bf16(a, vb0, oacc0, 0, 0, 0);
            oacc1 = __builtin_amdgcn_mfma_f32_16x16x32_bf16(a, vb1, oacc1, 0, 0, 0);
        }

        // ---- O store: bf16, [tok][136] padded rows; head slice is 64B-sector aligned ----
        #pragma unroll
        for (int r = 0; r < 4; ++r) {
            const size_t row = (size_t)(i * NJ) + tq + g * 4 + r;
            og[row * 136 + h * 32 + l16]      = f2bf(oacc0[r]);
            og[row * 136 + h * 32 + 16 + l16] = f2bf(oacc1[r]);
        }
    }
}

// ================= Kernel 3: out = O @ wo^T + bias =================
__global__ __launch_bounds__(512, 4)
void k_oproj(const char* __restrict__ ws, const float* __restrict__ wo,
             const float* __restrict__ wo_b, float* __restrict__ out)
{
    __shared__ short ol[128][136];   // 34,816 B

    const int tid  = threadIdx.x;
    const int lane = tid & 63;
    const int wid  = tid >> 6;
    const int g    = lane >> 4;
    const int l16  = lane & 15;
    const size_t tok0 = (size_t)blockIdx.x * 128;

    const char* ogp = ws + OG_OFF + tok0 * 272;
    for (int c = wid; c < 34; c += 8)
        load_lds16(ogp + c * 1024 + lane * 16, (char*)ol + c * 1024);
    __syncthreads();

    const int nt = wid;
    const float* wrow = wo + (size_t)(nt * 16 + l16) * NC + g * 8;
    bf16x8 bfr[4];
    #pragma unroll
    for (int ks_ = 0; ks_ < 4; ++ks_) {
        f32x4 a = *(const f32x4*)(wrow + ks_ * 32);
        f32x4 c = *(const f32x4*)(wrow + ks_ * 32 + 4);
        bf16x8 t8;
        #pragma unroll
        for (int e = 0; e < 4; ++e) { t8[e] = f2bf(a[e]); t8[4 + e] = f2bf(c[e]); }
        bfr[ks_] = t8;
    }
    const float bias = wo_b[nt * 16 + l16];
    const f32x4 z4 = {0.f, 0.f, 0.f, 0.f};

    #pragma unroll
    for (int mt = 0; mt < 8; ++mt) {
        const short* orow = &ol[mt * 16 + l16][g * 8];
        f32x4 acc = z4;
        #pragma unroll
        for (int ks_ = 0; ks_ < 4; ++ks_) {
            bf16x8 av = *(const bf16x8*)(orow + ks_ * 32);
            acc = __builtin_amdgcn_mfma_f32_16x16x32_bf16(av, bfr[ks_], acc, 0, 0, 0);
        }
        #pragma unroll
        for (int r = 0; r < 4; ++r)
            out[(tok0 + mt * 16 + g * 4 + r) * NC + nt * 16 + l16] = acc[r] + bias;
    }
}

extern "C" void kernel_launch(void* const* d_in, const int* in_sizes, int n_in,
                              void* d_out, int out_size, void* d_ws, size_t ws_size,
                              hipStream_t stream) {
    const float* x    = (const float*)d_in[0];
    const float* mask = (const float*)d_in[1];
    const float* ln_g = (const float*)d_in[2];
    const float* ln_b = (const float*)d_in[3];
    const float* wq   = (const float*)d_in[4];
    const float* wk   = (const float*)d_in[5];
    const float* wv   = (const float*)d_in[6];
    const float* wb   = (const float*)d_in[7];
    const float* wo   = (const float*)d_in[8];
    const float* wo_b = (const float*)d_in[9];
    float* out = (float*)d_out;
    char* ws   = (char*)d_ws;

    k_qkv<<<dim3(NI * 2), dim3(512), 0, stream>>>(x, mask, ln_g, ln_b, wq, wk, wv, wb, ws);
    k_attn<<<dim3(NI * NH), dim3(512), 0, stream>>>(ws, (short*)(ws + OG_OFF));
    k_oproj<<<dim3(NI * 2), dim3(512), 0, stream>>>(ws, wo, wo_b, out);
}

// Round 3
// 95.576 us; speedup vs baseline: 1.6115x; 1.6115x over previous
//
#include <hip/hip_runtime.h>
#include <hip/hip_bf16.h>

typedef short bf16x8 __attribute__((ext_vector_type(8)));
typedef short bf16x4 __attribute__((ext_vector_type(4)));
typedef float f32x4  __attribute__((ext_vector_type(4)));

#define NI 256
#define NJ 256
#define NC 128
#define NH 4
#define ND 32

// ---- workspace layout (bytes) ----
#define WB_OFF    0           // wqkv bf16 [384][128]
#define WO_BF_OFF 98304       // wo bf16 [128][128]
#define QG_OFF    131072      // [1024 ih][256 tok][32] bf16
#define KG_OFF    16908288    // [1024 ih][256 tok][40] bf16 (pad cols 32..39 garbage)
#define VTG_OFF   37879808    // [1024 ih][32 d][264 tok] bf16 (16896 B per ih)
#define TBM_OFF   55181312    // [1024 ih][256] f32  (tb + mask bias)
#define OG_OFF    56229888    // [65536 tok][136] bf16 (cols 128..135 pad)
// end = 74,055,680 bytes (< round-2 proven 74,448,896)

__device__ __forceinline__ short f2bf(float f) {
    return __builtin_bit_cast(short, __float2bfloat16(f));
}

typedef __attribute__((address_space(1))) const void gvoid_t;
typedef __attribute__((address_space(3))) void svoid_t;
__device__ __forceinline__ void load_lds16(const void* g, void* l) {
    __builtin_amdgcn_global_load_lds((gvoid_t*)g, (svoid_t*)l, 16, 0, 0);
}

// ================= k_conv: weights f32 -> bf16 (once) =================
__global__ __launch_bounds__(256, 8)
void k_conv(const float* __restrict__ wq, const float* __restrict__ wk,
            const float* __restrict__ wv, const float* __restrict__ wo,
            char* __restrict__ ws)
{
    const int gt = blockIdx.x * 256 + threadIdx.x;   // grid 64 -> 16384 threads
    const int base = gt * 4;                          // 65536 elems total
    const float* src;
    short* dst;
    if (base < 49152) {
        const int t = base >> 14;                     // 0=q 1=k 2=v
        src = (t == 0 ? wq : (t == 1 ? wk : wv)) + (base & 16383);
        dst = (short*)(ws + WB_OFF) + base;
    } else {
        src = wo + (base - 49152);
        dst = (short*)(ws + WO_BF_OFF) + (base - 49152);
    }
    f32x4 v = *(const f32x4*)src;
    bf16x4 o;
    #pragma unroll
    for (int r = 0; r < 4; ++r) o[r] = f2bf(v[r]);
    *(bf16x4*)dst = o;
}

// ================= k_pre: LN + tb + QKV projection =================
__global__ __launch_bounds__(512, 4)   // 128 VGPR, 2 blocks/CU (LDS 32KB)
void k_pre(const float* __restrict__ x, const float* __restrict__ mask,
           const float* __restrict__ ln_g, const float* __restrict__ ln_b,
           const float* __restrict__ wb, char* __restrict__ ws)
{
    __shared__ char xn_s[128 * 256];   // 32KB; row t: 16 chunks of 16B, chunk' = chunk ^ (t&7)

    const int tid  = threadIdx.x;
    const int lane = tid & 63;
    const int wid  = tid >> 6;
    const int g    = lane >> 4;
    const int l16  = lane & 15;
    const int b    = blockIdx.x;
    const int i    = b >> 1;
    const int half = b & 1;
    const int j0   = half * 128;

    // ---- phase 1: LN (4 threads per token, 32 ch each) + tb + mask bias ----
    {
        const int t  = tid >> 2;
        const int p  = tid & 3;
        const int ch = p * 32;
        const float* xr = x + ((size_t)(i * NJ) + j0 + t) * NC + ch;
        f32x4 vx[8];
        float s0 = 0.f;
        #pragma unroll
        for (int u = 0; u < 8; ++u) {
            vx[u] = *(const f32x4*)(xr + 4 * u);
            s0 += vx[u][0] + vx[u][1] + vx[u][2] + vx[u][3];
        }
        s0 += __shfl_xor(s0, 1);
        s0 += __shfl_xor(s0, 2);
        const float mu = s0 * 0.0078125f;
        float v0 = 0.f;
        #pragma unroll
        for (int u = 0; u < 8; ++u) {
            #pragma unroll
            for (int e = 0; e < 4; ++e) { float d = vx[u][e] - mu; v0 += d * d; }
        }
        v0 += __shfl_xor(v0, 1);
        v0 += __shfl_xor(v0, 2);
        const float rs = rsqrtf(v0 * 0.0078125f + 1e-5f);
        #pragma unroll
        for (int u = 0; u < 8; ++u) {
            f32x4 gg = *(const f32x4*)(ln_g + ch + 4 * u);
            f32x4 bb = *(const f32x4*)(ln_b + ch + 4 * u);
            #pragma unroll
            for (int e = 0; e < 4; ++e) vx[u][e] = (vx[u][e] - mu) * rs * gg[e] + bb[e];
        }
        // tb: per-head dot with wb (f32), reduce over the 4 token-threads
        float tb[4];
        #pragma unroll
        for (int h = 0; h < 4; ++h) {
            const float* wr = wb + h * NC + ch;
            float a = 0.f;
            #pragma unroll
            for (int u = 0; u < 8; ++u) {
                f32x4 w4 = *(const f32x4*)(wr + 4 * u);
                #pragma unroll
                for (int e = 0; e < 4; ++e) a += vx[u][e] * w4[e];
            }
            a += __shfl_xor(a, 1);
            a += __shfl_xor(a, 2);
            tb[h] = a;
        }
        if (p == 0) {
            const float mb = 1.0e9f * (mask[(size_t)i * NJ + j0 + t] - 1.0f);
            float* tbm = (float*)(ws + TBM_OFF);
            #pragma unroll
            for (int h = 0; h < 4; ++h)
                tbm[((size_t)(i * NH) + h) * NJ + j0 + t] = tb[h] + mb;
        }
        // write xn bf16 to LDS, XOR-swizzled chunks
        #pragma unroll
        for (int cc = 0; cc < 4; ++cc) {
            bf16x8 o8;
            #pragma unroll
            for (int e = 0; e < 4; ++e) {
                o8[e]     = f2bf(vx[2 * cc][e]);
                o8[4 + e] = f2bf(vx[2 * cc + 1][e]);
            }
            const int chunk = (p * 4 + cc) ^ (t & 7);
            *(bf16x8*)(xn_s + t * 256 + chunk * 16) = o8;
        }
    }
    __syncthreads();

    // ---- phase 2: QKV GEMM; wave owns 48 W-rows (register B-fragments) ----
    const f32x4 z4 = {0.f, 0.f, 0.f, 0.f};
    bf16x8 bfr[3][4];
    #pragma unroll
    for (int s = 0; s < 3; ++s) {
        const int n0 = wid * 48 + s * 16;
        const short* wr = (const short*)(ws + WB_OFF) + (size_t)(n0 + l16) * NC + g * 8;
        #pragma unroll
        for (int ks = 0; ks < 4; ++ks) bfr[s][ks] = *(const bf16x8*)(wr + ks * 32);
    }

    for (int mt = 0; mt < 8; ++mt) {
        const int row = mt * 16 + l16;
        bf16x8 af[4];
        #pragma unroll
        for (int ks = 0; ks < 4; ++ks) {
            const int chunk = (ks * 4 + g) ^ (row & 7);
            af[ks] = *(const bf16x8*)(xn_s + row * 256 + chunk * 16);
        }
        #pragma unroll
        for (int s = 0; s < 3; ++s) {
            f32x4 acc = z4;
            #pragma unroll
            for (int ks = 0; ks < 4; ++ks)
                acc = __builtin_amdgcn_mfma_f32_16x16x32_bf16(af[ks], bfr[s][ks], acc, 0, 0, 0);

            const int gr  = wid * 48 + s * 16;     // global W-row base (multiple of 16)
            const int buf = gr >> 7;               // 0=q 1=k 2=v
            const int h   = (gr >> 5) & 3;
            const int dd0 = gr & 31;               // 0 or 16
            const size_t ih = (size_t)(i * NH) + h;
            const int tok = j0 + mt * 16 + g * 4;
            if (buf == 0) {
                short* qg = (short*)(ws + QG_OFF) + ih * 8192;
                #pragma unroll
                for (int r = 0; r < 4; ++r) qg[(tok + r) * 32 + dd0 + l16] = f2bf(acc[r]);
            } else if (buf == 1) {
                short* kg = (short*)(ws + KG_OFF) + ih * 10240;
                #pragma unroll
                for (int r = 0; r < 4; ++r) kg[(tok + r) * 40 + dd0 + l16] = f2bf(acc[r]);
            } else {
                short* vt = (short*)(ws + VTG_OFF) + ih * 8448;
                bf16x4 pk;
                #pragma unroll
                for (int r = 0; r < 4; ++r) pk[r] = f2bf(acc[r]);
                *(bf16x4*)(vt + (size_t)(dd0 + l16) * 264 + tok) = pk;
            }
        }
    }
}

// ================= k_attn: per-(i,h) attention =================
__global__ __launch_bounds__(512, 4)   // 128 VGPR
void k_attn(char* __restrict__ ws)
{
    __shared__ short kls[256][40];        // 20,480 B
    __shared__ char  vls[17408];          // 16,896 used; rest pad
    __shared__ short pbuf[8][2][16][40];  // 20,480 B  (total 58,368 B)

    const int tid  = threadIdx.x;
    const int lane = tid & 63;
    const int wid  = tid >> 6;
    const int g    = lane >> 4;
    const int l16  = lane & 15;
    const size_t ih = blockIdx.x;
    const int i = (int)(ih >> 2);
    const int h = (int)(ih & 3);

    const short* qg  = (const short*)(ws + QG_OFF) + ih * 8192;
    const char*  kgp = ws + KG_OFF + ih * 20480;
    const char*  vtp = ws + VTG_OFF + ih * 16896;
    const float* tbm = (const float*)(ws + TBM_OFF) + ih * NJ;
    short* og = (short*)(ws + OG_OFF);

    // ---- stage K (20KB) + vT (16.5KB) ----
    for (int c = wid; c < 37; c += 8) {
        if (c < 20)      load_lds16(kgp + c * 1024 + lane * 16, (char*)kls + c * 1024);
        else if (c < 36) load_lds16(vtp + (c - 20) * 1024 + lane * 16, vls + (c - 20) * 1024);
        else if (lane < 32) load_lds16(vtp + 16384 + lane * 16, vls + 16384);
    }
    __syncthreads();

    const float SCALE = 0.17677669529663687f;  // 1/sqrt(32)
    const f32x4 z4 = {0.f, 0.f, 0.f, 0.f};

    #pragma unroll
    for (int qt = 0; qt < 2; ++qt) {
        const int tq = wid * 32 + qt * 16;
        f32x4 tbmb = *(const f32x4*)(tbm + tq + g * 4);

        bf16x8 qf = *(const bf16x8*)(qg + (size_t)(tq + l16) * 32 + g * 8);
        f32x4 s[16];
        #pragma unroll
        for (int kt = 0; kt < 16; ++kt) {
            bf16x8 kf = *(const bf16x8*)(&kls[kt * 16 + l16][g * 8]);
            s[kt] = __builtin_amdgcn_mfma_f32_16x16x32_bf16(qf, kf, z4, 0, 0, 0);
        }
        #pragma unroll
        for (int kt = 0; kt < 16; ++kt)
            #pragma unroll
            for (int r = 0; r < 4; ++r)
                s[kt][r] = fmaf(s[kt][r], SCALE, tbmb[r]);  // fp32: masked rows collapse exactly

        f32x4 mx = s[0];
        #pragma unroll
        for (int kt = 1; kt < 16; ++kt)
            #pragma unroll
            for (int r = 0; r < 4; ++r) mx[r] = fmaxf(mx[r], s[kt][r]);
        #pragma unroll
        for (int d = 1; d < 16; d <<= 1)
            #pragma unroll
            for (int r = 0; r < 4; ++r) mx[r] = fmaxf(mx[r], __shfl_xor(mx[r], d));

        f32x4 sum = z4;
        #pragma unroll
        for (int kt = 0; kt < 16; ++kt)
            #pragma unroll
            for (int r = 0; r < 4; ++r) { s[kt][r] = __expf(s[kt][r] - mx[r]); sum[r] += s[kt][r]; }
        #pragma unroll
        for (int d = 1; d < 16; d <<= 1)
            #pragma unroll
            for (int r = 0; r < 4; ++r) sum[r] += __shfl_xor(sum[r], d);
        f32x4 inv;
        #pragma unroll
        for (int r = 0; r < 4; ++r) inv[r] = 1.0f / sum[r];
        #pragma unroll
        for (int kt = 0; kt < 16; ++kt)
            #pragma unroll
            for (int r = 0; r < 4; ++r) s[kt][r] *= inv[r];

        // ---- PV: double-buffered per-wave LDS staging, 32-key chunks ----
        f32x4 oacc0 = z4, oacc1 = z4;
        #pragma unroll
        for (int c = 0; c < 8; ++c) {
            short* pb = &pbuf[wid][c & 1][0][0];
            #pragma unroll
            for (int kk = 0; kk < 2; ++kk) {
                #pragma unroll
                for (int r = 0; r < 4; ++r)
                    pb[(g * 4 + r) * 40 + kk * 16 + l16] = f2bf(s[c * 2 + kk][r]);
            }
            bf16x8 a   = *(const bf16x8*)(pb + l16 * 40 + g * 8);
            bf16x8 vb0 = *(const bf16x8*)((const short*)(vls + (size_t)l16 * 528) + c * 32 + g * 8);
            bf16x8 vb1 = *(const bf16x8*)((const short*)(vls + (size_t)(16 + l16) * 528) + c * 32 + g * 8);
            oacc0 = __builtin_amdgcn_mfma_f32_16x16x32_bf16(a, vb0, oacc0, 0, 0, 0);
            oacc1 = __builtin_amdgcn_mfma_f32_16x16x32_bf16(a, vb1, oacc1, 0, 0, 0);
        }

        // ---- O store ----
        #pragma unroll
        for (int r = 0; r < 4; ++r) {
            const size_t row = (size_t)(i * NJ) + tq + g * 4 + r;
            og[row * 136 + h * 32 + l16]      = f2bf(oacc0[r]);
            og[row * 136 + h * 32 + 16 + l16] = f2bf(oacc1[r]);
        }
    }
}

// ================= k_oproj: out = O @ wo^T + bias =================
__global__ __launch_bounds__(512, 4)
void k_oproj(const char* __restrict__ ws, const float* __restrict__ wo_b,
             float* __restrict__ out)
{
    __shared__ short ol[128][136];   // 34,816 B

    const int tid  = threadIdx.x;
    const int lane = tid & 63;
    const int wid  = tid >> 6;
    const int g    = lane >> 4;
    const int l16  = lane & 15;
    const size_t tok0 = (size_t)blockIdx.x * 128;

    const char* ogp = ws + OG_OFF + tok0 * 272;
    for (int c = wid; c < 34; c += 8)
        load_lds16(ogp + c * 1024 + lane * 16, (char*)ol + c * 1024);
    __syncthreads();

    const short* wrow = (const short*)(ws + WO_BF_OFF) + (size_t)(wid * 16 + l16) * NC + g * 8;
    bf16x8 bfr[4];
    #pragma unroll
    for (int ks = 0; ks < 4; ++ks) bfr[ks] = *(const bf16x8*)(wrow + ks * 32);

    const float bias = wo_b[wid * 16 + l16];
    const f32x4 z4 = {0.f, 0.f, 0.f, 0.f};

    #pragma unroll
    for (int mt = 0; mt < 8; ++mt) {
        const short* orow = &ol[mt * 16 + l16][g * 8];
        f32x4 acc = z4;
        #pragma unroll
        for (int ks = 0; ks < 4; ++ks) {
            bf16x8 av = *(const bf16x8*)(orow + ks * 32);
            acc = __builtin_amdgcn_mfma_f32_16x16x32_bf16(av, bfr[ks], acc, 0, 0, 0);
        }
        #pragma unroll
        for (int r = 0; r < 4; ++r)
            out[(tok0 + mt * 16 + g * 4 + r) * NC + wid * 16 + l16] = acc[r] + bias;
    }
}

extern "C" void kernel_launch(void* const* d_in, const int* in_sizes, int n_in,
                              void* d_out, int out_size, void* d_ws, size_t ws_size,
                              hipStream_t stream) {
    const float* x    = (const float*)d_in[0];
    const float* mask = (const float*)d_in[1];
    const float* ln_g = (const float*)d_in[2];
    const float* ln_b = (const float*)d_in[3];
    const float* wq   = (const float*)d_in[4];
    const float* wk   = (const float*)d_in[5];
    const float* wv   = (const float*)d_in[6];
    const float* wb   = (const float*)d_in[7];
    const float* wo   = (const float*)d_in[8];
    const float* wo_b = (const float*)d_in[9];
    float* out = (float*)d_out;
    char* ws   = (char*)d_ws;

    k_conv<<<dim3(64), dim3(256), 0, stream>>>(wq, wk, wv, wo, ws);
    k_pre<<<dim3(NI * 2), dim3(512), 0, stream>>>(x, mask, ln_g, ln_b, wb, ws);
    k_attn<<<dim3(NI * NH), dim3(512), 0, stream>>>(ws);
    k_oproj<<<dim3(NI * 2), dim3(512), 0, stream>>>(ws, wo_b, out);
}